// Round 2
// baseline (188.352 us; speedup 1.0000x reference)
//
#include <hip/hip_runtime.h>
#include <stdint.h>

// ---------- types ----------
typedef __attribute__((ext_vector_type(8))) short s8v;   // 8 bf16 (4 VGPRs)
typedef __attribute__((ext_vector_type(4))) float f4v;   // MFMA accumulator

// ---------- helpers ----------
__device__ __forceinline__ unsigned short f2bf(float f) {
  unsigned u = __float_as_uint(f);
  u = u + 0x7FFFu + ((u >> 16) & 1u);   // RNE
  return (unsigned short)(u >> 16);
}
// monotone float->uint map: order(enc(a)) == order(a); 0 is below enc of any real float.
__device__ __forceinline__ unsigned encf(float f) {
  unsigned i = __float_as_uint(f);
  return (i & 0x80000000u) ? ~i : (i | 0x80000000u);
}
__device__ __forceinline__ float decf(unsigned u) {
  unsigned i = (u & 0x80000000u) ? (u & 0x7FFFFFFFu) : ~u;
  return __uint_as_float(i);
}
__device__ __forceinline__ void gload_lds16(const unsigned short* g, unsigned short* l) {
  __builtin_amdgcn_global_load_lds((const __attribute__((address_space(1))) void*)g,
                                   (__attribute__((address_space(3))) void*)l, 16, 0, 0);
}

// ---------- fused: q,a fp32->bf16; U -> Ut bf16 transposed; zero rmax/cmax + out ----------
__global__ void convert_kernel(const float4* __restrict__ q, const float4* __restrict__ a,
                               const float* __restrict__ U,
                               ushort4* __restrict__ qb, ushort4* __restrict__ ab,
                               unsigned short* __restrict__ Ut,
                               unsigned* __restrict__ rcmax, float* __restrict__ out) {
  const int bx = blockIdx.x;
  if (bx < 8192) {
    const int i = bx * 256 + threadIdx.x;
    float4 v = q[i];
    qb[i] = make_ushort4(f2bf(v.x), f2bf(v.y), f2bf(v.z), f2bf(v.w));
    float4 w = a[i];
    ab[i] = make_ushort4(f2bf(w.x), f2bf(w.y), f2bf(w.z), f2bf(w.w));
  } else if (bx < 8256) {
    // U transpose: 64 blocks x 256 thr, 4 elements each (tiny: 256 KB read)
    const int idx = (bx - 8192) * 256 + threadIdx.x;   // 0..16383
    const int n  = idx >> 6;
    const int k4 = (idx & 63) * 4;
    ushort4 o;
    o.x = f2bf(U[(k4 + 0) * 256 + n]);
    o.y = f2bf(U[(k4 + 1) * 256 + n]);
    o.z = f2bf(U[(k4 + 2) * 256 + n]);
    o.w = f2bf(U[(k4 + 3) * 256 + n]);
    *(ushort4*)&Ut[n * 256 + k4] = o;
  } else if (bx < 8320) {
    // zero rmax+cmax (64K uints): 64 blocks x 256 thr x 4
    const int idx = (bx - 8256) * 256 + threadIdx.x;   // 0..16383
    *(uint4*)&rcmax[idx * 4] = make_uint4(0u, 0u, 0u, 0u);
  } else {
    // zero out (8192 floats): 32 blocks (stream-ordered before wsum's atomics)
    out[(bx - 8320) * 256 + threadIdx.x] = 0.f;
  }
}

// ---------- fused qU-GEMM + S-max: one block per (batch, 128-row slab) ----------
// R15: R14's structure (qU A-frags register-hoisted once; double-buffered a-tile
// staging with counted vmcnt(8)) was correct — counters confirmed the LDS-traffic
// drop (bank-conflicts 6.3M->2.4M) — but the allocator targeted 4 waves/EU
// (VGPR_Count=128) and SPILLED the 128-VGPR aq array to scratch: WRITE_SIZE
// 2.2MB->24MB, FETCH +11MB, 85us. This kernel runs 1 block/CU (139776B LDS) =
// 8 waves = exactly 2 waves/EU, so a 256-VGPR budget is free.
// Fix: amdgpu_waves_per_eu(2,2) pins the allocator to the real occupancy.
//  (a) qU A-fragments hoisted to registers ONCE (aq[4][8] = 128 VGPR) — qU is
//      invariant across the 16 a-tiles; cuts 256 KB/tile of LDS re-reads.
//  (b) qUs LDS region dead after hoist -> 2nd staging buffer; a-tile staging
//      double-buffered with `s_waitcnt vmcnt(8)` + raw s_barrier (never
//      vmcnt(0) mid-loop): tile t+1's 8 global_load_lds fly under tile t's
//      compute (T3/T4 pattern).
//  Per-tile LDS traffic: 448 KB -> 192 KB (B reads 128 KB + stage 64 KB).
// Phase 1 (single pass): qU_tile[128][256] = qb_tile[128x256] @ Ut[256x256],
//   wave grid 2x4 (64x64 tiles), staged K=64 slices; result -> qUs LDS,
//   XOR-swizzled row-major (16B chunk c at c ^ (row&7)).
// Grid (b, tm): linear%8 == b%8 pins each batch to one XCD L2.
__global__ __attribute__((amdgpu_flat_work_group_size(512, 512), amdgpu_waves_per_eu(2, 2)))
void fused_qu_smax(const unsigned short* __restrict__ qb,
                   const unsigned short* __restrict__ Ut,
                   const unsigned short* __restrict__ ab,
                   unsigned* __restrict__ rowmax,
                   unsigned* __restrict__ colmax) {
  extern __shared__ char smem[];
  unsigned short* qUs    = (unsigned short*)smem;             // 64 KB: qU tile, then stage buf B
  unsigned short* Bs2    = (unsigned short*)(smem + 65536);   // 64 KB: staging buf A
  unsigned*       colLds = (unsigned*)(smem + 131072);        // 8 KB
  unsigned*       rowLds = (unsigned*)(smem + 139264);        // 512 B

  const int tid = threadIdx.x;
  const int b = blockIdx.x, tm = blockIdx.y;

  const int lane = tid & 63;
  const int m16  = lane & 15;
  const int quad = lane >> 4;
  const int wave = tid >> 6;          // 0..7
  const int wm   = wave >> 2;         // 0..1 (row half)
  const int wn   = wave & 3;          // 0..3
  const int srow = tid >> 3;          // staging row (64/issue)
  const int scol = (((tid & 7) ^ (srow & 7))) * 8;   // swizzled source chunk

  #pragma unroll
  for (int i = 0; i < 4; ++i) colLds[i * 512 + tid] = 0u;
  if (tid < 128) rowLds[tid] = 0u;

  // ================= phase 1: qU tile -> LDS (single pass) =================
  const unsigned short* Aq = qb + ((long)b * 2048 + tm * 128) * 256;
  unsigned short* S1 = Bs2;            // 16 KB: A 128x64
  unsigned short* S2 = Bs2 + 8192;     // 32 KB: B 256x64
  {
    f4v acc[4][4] = {};
    for (int kt = 0; kt < 4; ++kt) {
      const int k0 = kt * 64;
      __syncthreads();                 // staging region free
      #pragma unroll
      for (int i = 0; i < 2; ++i)
        gload_lds16(Aq + (long)(i * 64 + srow) * 256 + k0 + scol, &S1[i * 4096 + tid * 8]);
      #pragma unroll
      for (int i = 0; i < 4; ++i)
        gload_lds16(Ut + (long)(i * 64 + srow) * 256 + k0 + scol, &S2[i * 4096 + tid * 8]);
      __syncthreads();                 // staging complete
      #pragma unroll
      for (int kk = 0; kk < 2; ++kk) {
        const int cs = ((kk * 4 + quad) ^ (m16 & 7)) * 8;
        s8v af[4], bfv[4];
        #pragma unroll
        for (int i = 0; i < 4; ++i)
          af[i] = *(const s8v*)&S1[(wm * 64 + i * 16 + m16) * 64 + cs];
        #pragma unroll
        for (int j = 0; j < 4; ++j)
          bfv[j] = *(const s8v*)&S2[(wn * 64 + j * 16 + m16) * 64 + cs];
        #pragma unroll
        for (int i = 0; i < 4; ++i)
          #pragma unroll
          for (int j = 0; j < 4; ++j)
            acc[i][j] = __builtin_amdgcn_mfma_f32_16x16x32_bf16(af[i], bfv[j], acc[i][j], 0, 0, 0);
      }
    }
    // write acc -> qUs (row-major 256 cols, swizzled 16B chunks)
    // C/D layout: col = lane&15, row = quad*4 + reg (verified mapping)
    #pragma unroll
    for (int i = 0; i < 4; ++i)
      #pragma unroll
      for (int r = 0; r < 4; ++r) {
        const int lr = wm * 64 + i * 16 + quad * 4 + r;
        #pragma unroll
        for (int j = 0; j < 4; ++j) {
          const int col = wn * 64 + j * 16 + m16;
          const int ch = (col >> 3) ^ (lr & 7);
          qUs[lr * 256 + ch * 8 + (col & 7)] = f2bf(acc[i][j][r]);
        }
      }
  }
  __syncthreads();   // qUs complete; Bs2 free for phase 2

  // ================= phase 2: 16 a-tiles vs register-resident qU =================
  const unsigned short* Ab_ = ab + (long)b * 2048 * 256;

  auto stage = [&](int tb, unsigned short* dst) {
    #pragma unroll
    for (int e = 0; e < 8; ++e) {
      const int u = e * 512 + tid;          // 16B unit: row = u>>5, chunk = u&31
      const int row = u >> 5;
      const int chs = (u & 31) ^ (row & 7);
      gload_lds16(Ab_ + (long)(tb * 128 + row) * 256 + chs * 8, &dst[u * 8]);
    }
  };

  // issue tile-0 staging first so the globals fly during the A-frag hoist
  stage(0, Bs2);

  // hoist qU A-fragments: invariant across all 16 tiles (128 VGPRs)
  s8v aq[4][8];
  #pragma unroll
  for (int kq = 0; kq < 8; ++kq) {
    const int cs = ((kq * 4 + quad) ^ (m16 & 7)) * 8;
    #pragma unroll
    for (int i = 0; i < 4; ++i)
      aq[i][kq] = *(const s8v*)&qUs[(wm * 64 + i * 16 + m16) * 256 + cs];
  }
  // all waves must have their qU reads DATA-RETURNED before qUs is restaged
  asm volatile("s_waitcnt lgkmcnt(0)" ::: "memory");
  __builtin_amdgcn_s_barrier();

  float rmx[4][4];
  #pragma unroll
  for (int i = 0; i < 4; ++i)
    #pragma unroll
    for (int r = 0; r < 4; ++r) rmx[i][r] = -3.4e38f;

  auto compute = [&](int tb, const unsigned short* buf) {
    f4v acc[4][2] = {};
    #pragma unroll
    for (int kq = 0; kq < 8; ++kq) {
      const int cs = ((kq * 4 + quad) ^ (m16 & 7)) * 8;
      s8v bfv[2];
      #pragma unroll
      for (int j = 0; j < 2; ++j)
        bfv[j] = *(const s8v*)&buf[(wn * 32 + j * 16 + m16) * 256 + cs];
      #pragma unroll
      for (int i = 0; i < 4; ++i)
        #pragma unroll
        for (int j = 0; j < 2; ++j)
          acc[i][j] = __builtin_amdgcn_mfma_f32_16x16x32_bf16(aq[i][kq], bfv[j], acc[i][j], 0, 0, 0);
    }
    // per-tile reductions: rows -> running per-lane max; cols -> LDS atomicMax
    #pragma unroll
    for (int i = 0; i < 4; ++i)
      #pragma unroll
      for (int r = 0; r < 4; ++r)
        rmx[i][r] = fmaxf(rmx[i][r], fmaxf(acc[i][0][r], acc[i][1][r]));
    #pragma unroll
    for (int j = 0; j < 2; ++j) {
      float v = -3.4e38f;
      #pragma unroll
      for (int i = 0; i < 4; ++i)
        #pragma unroll
        for (int r = 0; r < 4; ++r) v = fmaxf(v, acc[i][j][r]);
      v = fmaxf(v, __shfl_xor(v, 16));
      v = fmaxf(v, __shfl_xor(v, 32));
      if (quad == 0) atomicMax(&colLds[tb * 128 + wn * 32 + j * 16 + m16], encf(v));
    }
  };

  // double-buffered pipeline: stage(t+1) issued BEFORE compute(t); counted
  // vmcnt(8) keeps the next tile's 8 loads in flight across the barrier.
  #pragma unroll 1
  for (int t2 = 0; t2 < 8; ++t2) {
    const int te = t2 * 2;
    // ---- even tile: compute Bs2, stage te+1 -> qUs-region ----
    stage(te + 1, qUs);
    asm volatile("s_waitcnt vmcnt(8)" ::: "memory");   // tile te's loads landed
    __builtin_amdgcn_s_barrier();
    compute(te, Bs2);
    __builtin_amdgcn_s_barrier();                      // Bs2 reads done -> restage-safe
    // ---- odd tile: compute qUs-region, stage te+2 -> Bs2 ----
    if (te + 2 < 16) {
      stage(te + 2, Bs2);
      asm volatile("s_waitcnt vmcnt(8)" ::: "memory"); // tile te+1's loads landed
    } else {
      asm volatile("s_waitcnt vmcnt(0)" ::: "memory"); // drain for last tile
    }
    __builtin_amdgcn_s_barrier();
    compute(te + 1, qUs);
    __builtin_amdgcn_s_barrier();                      // qUs reads done -> restage-safe
  }

  // ---- final row maxes: shuffle over m16, combine wn-waves via LDS, store ----
  #pragma unroll
  for (int i = 0; i < 4; ++i)
    #pragma unroll
    for (int r = 0; r < 4; ++r) {
      float v = rmx[i][r];
      #pragma unroll
      for (int d2 = 1; d2 < 16; d2 <<= 1) v = fmaxf(v, __shfl_xor(v, d2));
      if (m16 == 0) atomicMax(&rowLds[wm * 64 + i * 16 + quad * 4 + r], encf(v));
    }
  __syncthreads();
  if (tid < 128)
    rowmax[(long)b * 2048 + tm * 128 + tid] = rowLds[tid];   // plain store (block owns rows)
  // ---- col maxes: one global atomic pass ----
  #pragma unroll
  for (int i = 0; i < 4; ++i)
    atomicMax(&colmax[(long)b * 2048 + i * 512 + tid], colLds[i * 512 + tid]);
}

// ---------- fused softmax + weighted sum (bf16 inputs, 16B/lane loads) ----------
__global__ void wsum_kernel(const uint4* __restrict__ qb, const uint4* __restrict__ ab,
                            const unsigned* __restrict__ rowmax, const unsigned* __restrict__ colmax,
                            float* __restrict__ out) {
  const int tid = threadIdx.x;
  const int chunk = blockIdx.x;
  const int b = blockIdx.y;
  const int z = blockIdx.z;
  const unsigned* e = z ? colmax : rowmax;
  const uint4* src = z ? ab : qb;

  __shared__ float sm[4];
  __shared__ float ss[4];
  __shared__ float wLds[128];
  __shared__ float red[256 * 8];   // 8 KB

  float x[8];
  float m = -3.4e38f;
  #pragma unroll
  for (int j = 0; j < 8; ++j) {
    x[j] = tanhf(decf(e[b * 2048 + j * 256 + tid]));
    m = fmaxf(m, x[j]);
  }
  #pragma unroll
  for (int d2 = 1; d2 < 64; d2 <<= 1) m = fmaxf(m, __shfl_xor(m, d2));
  if ((tid & 63) == 0) sm[tid >> 6] = m;
  __syncthreads();
  m = fmaxf(fmaxf(sm[0], sm[1]), fmaxf(sm[2], sm[3]));
  float s = 0.f;
  #pragma unroll
  for (int j = 0; j < 8; ++j) s += expf(x[j] - m);
  #pragma unroll
  for (int d2 = 1; d2 < 64; d2 <<= 1) s += __shfl_xor(s, d2);
  if ((tid & 63) == 0) ss[tid >> 6] = s;
  __syncthreads();
  const float inv = 1.f / (ss[0] + ss[1] + ss[2] + ss[3]);

  if (tid < 128) {
    float xv = tanhf(decf(e[b * 2048 + chunk * 128 + tid]));
    wLds[tid] = expf(xv - m) * inv;
  }
  __syncthreads();

  const int dg = tid & 31;
  const int rg = tid >> 5;       // 0..7, rows stride 8
  float acc[8] = {};
  const long rowbase = (long)b * 2048 + chunk * 128;
  for (int t = rg; t < 128; t += 8) {
    const float wgt = wLds[t];
    uint4 v = src[(rowbase + t) * 32 + dg];
    acc[0] += wgt * __uint_as_float(v.x << 16);
    acc[1] += wgt * __uint_as_float(v.x & 0xFFFF0000u);
    acc[2] += wgt * __uint_as_float(v.y << 16);
    acc[3] += wgt * __uint_as_float(v.y & 0xFFFF0000u);
    acc[4] += wgt * __uint_as_float(v.z << 16);
    acc[5] += wgt * __uint_as_float(v.z & 0xFFFF0000u);
    acc[6] += wgt * __uint_as_float(v.w << 16);
    acc[7] += wgt * __uint_as_float(v.w & 0xFFFF0000u);
  }
  #pragma unroll
  for (int k = 0; k < 8; ++k) red[tid * 8 + k] = acc[k];
  __syncthreads();
  if (tid < 32) {
    #pragma unroll
    for (int k = 0; k < 8; ++k) {
      float v = 0.f;
      #pragma unroll
      for (int g = 0; g < 8; ++g) v += red[((g << 5) | tid) * 8 + k];
      atomicAdd(&out[z * 4096 + b * 256 + tid * 8 + k], v);
    }
  }
}

// ---------- launch ----------
extern "C" void kernel_launch(void* const* d_in, const int* in_sizes, int n_in,
                              void* d_out, int out_size, void* d_ws, size_t ws_size,
                              hipStream_t stream) {
  const float* q = (const float*)d_in[0];
  const float* a = (const float*)d_in[1];
  const float* U = (const float*)d_in[2];
  float* out = (float*)d_out;

  char* w = (char*)d_ws;
  unsigned short* qb = (unsigned short*)w;                       // 16 MB
  unsigned short* ab = (unsigned short*)(w + (16ull << 20));     // 16 MB
  unsigned short* Ut = (unsigned short*)(w + (32ull << 20));     // 128 KB
  unsigned* rmax = (unsigned*)(w + (32ull << 20) + (128ull << 10));
  unsigned* cmax = rmax + 32768;

  // allow 139776 B dynamic LDS for the fused kernel (host-side, idempotent)
  constexpr int SMEM = 139776;
  hipFuncSetAttribute((const void*)fused_qu_smax,
                      hipFuncAttributeMaxDynamicSharedMemorySize, SMEM);

  // fused q/a bf16-cast + U transpose + rmax/cmax zero + out zero
  convert_kernel<<<8352, 256, 0, stream>>>((const float4*)q, (const float4*)a, U,
                                           (ushort4*)qb, (ushort4*)ab, Ut, rmax, out);

  // qU tile in LDS + S row/col maxes; grid (b, tm) -> XCD == b%8; 8 waves/block
  fused_qu_smax<<<dim3(16, 16), 512, SMEM, stream>>>(qb, Ut, ab, rmax, cmax);

  // fused softmax + weighted pooling (bf16, 16B/lane)
  wsum_kernel<<<dim3(16, 16, 2), 256, 0, stream>>>((const uint4*)qb, (const uint4*)ab,
                                                   rmax, cmax, out);
}

// Round 3
// 158.399 us; speedup vs baseline: 1.1891x; 1.1891x over previous
//
#include <hip/hip_runtime.h>
#include <stdint.h>

// ---------- types ----------
typedef __attribute__((ext_vector_type(8))) short s8v;   // 8 bf16 (4 VGPRs)
typedef __attribute__((ext_vector_type(4))) float f4v;   // MFMA accumulator

// ---------- helpers ----------
__device__ __forceinline__ unsigned short f2bf(float f) {
  unsigned u = __float_as_uint(f);
  u = u + 0x7FFFu + ((u >> 16) & 1u);   // RNE
  return (unsigned short)(u >> 16);
}
// monotone float->uint map: order(enc(a)) == order(a); 0 is below enc of any real float.
__device__ __forceinline__ unsigned encf(float f) {
  unsigned i = __float_as_uint(f);
  return (i & 0x80000000u) ? ~i : (i | 0x80000000u);
}
__device__ __forceinline__ float decf(unsigned u) {
  unsigned i = (u & 0x80000000u) ? (u & 0x7FFFFFFFu) : ~u;
  return __uint_as_float(i);
}
__device__ __forceinline__ void gload_lds16(const unsigned short* g, unsigned short* l) {
  __builtin_amdgcn_global_load_lds((const __attribute__((address_space(1))) void*)g,
                                   (__attribute__((address_space(3))) void*)l, 16, 0, 0);
}

// ---------- fused: q,a fp32->bf16; U -> Ut bf16 transposed; zero rmax/cmax + out ----------
__global__ void convert_kernel(const float4* __restrict__ q, const float4* __restrict__ a,
                               const float* __restrict__ U,
                               ushort4* __restrict__ qb, ushort4* __restrict__ ab,
                               unsigned short* __restrict__ Ut,
                               unsigned* __restrict__ rcmax, float* __restrict__ out) {
  const int bx = blockIdx.x;
  if (bx < 8192) {
    const int i = bx * 256 + threadIdx.x;
    float4 v = q[i];
    qb[i] = make_ushort4(f2bf(v.x), f2bf(v.y), f2bf(v.z), f2bf(v.w));
    float4 w = a[i];
    ab[i] = make_ushort4(f2bf(w.x), f2bf(w.y), f2bf(w.z), f2bf(w.w));
  } else if (bx < 8256) {
    // U transpose: 64 blocks x 256 thr, 4 elements each (tiny: 256 KB read)
    const int idx = (bx - 8192) * 256 + threadIdx.x;   // 0..16383
    const int n  = idx >> 6;
    const int k4 = (idx & 63) * 4;
    ushort4 o;
    o.x = f2bf(U[(k4 + 0) * 256 + n]);
    o.y = f2bf(U[(k4 + 1) * 256 + n]);
    o.z = f2bf(U[(k4 + 2) * 256 + n]);
    o.w = f2bf(U[(k4 + 3) * 256 + n]);
    *(ushort4*)&Ut[n * 256 + k4] = o;
  } else if (bx < 8320) {
    // zero rmax+cmax (64K uints): 64 blocks x 256 thr x 4
    const int idx = (bx - 8256) * 256 + threadIdx.x;   // 0..16383
    *(uint4*)&rcmax[idx * 4] = make_uint4(0u, 0u, 0u, 0u);
  } else {
    // zero out (8192 floats): 32 blocks (stream-ordered before wsum's atomics)
    out[(bx - 8320) * 256 + threadIdx.x] = 0.f;
  }
}

// ---------- fused qU-GEMM + S-max: one block per (batch, 128-row slab) ----------
// R16: R14/R15's 2x4-grid hoist (aq[4][8]=128 VGPR) spilled under a 128-VGPR
// allocator cap that neither __launch_bounds__(512,2) nor amdgpu_waves_per_eu(2,2)
// lifted (VGPR_Count=128 both rounds, WRITE_SIZE 23MB scratch). Fix: cut demand
// below the cap instead of fighting the allocator — phase-2 wave grid 4x2
// (32 rows x 64 cols per wave): aq[2][8] = 64 VGPRs; in-loop demand ~110-140.
// Tradeoff: B-slice read by 4 waves (was 2) -> per-tile LDS 320 KB vs R13's 448
// (A re-read eliminated entirely). Lambdas -> macros (no SROA risk).
// Counted-vmcnt(8) double-buffer pipeline unchanged (verified 2x):
//   stage(t+1) issued BEFORE compute(t); vmcnt never drained mid-loop.
// Phase 1 (unchanged, 2x4 grid): qU_tile[128][256] = qb[128x256] @ Ut[256x256],
//   staged K=64 slices; result -> qUs LDS, XOR-swizzled (16B chunk c ^ (row&7)).
// Grid (b, tm): linear%8 == b%8 pins each batch to one XCD L2.
__global__ __attribute__((amdgpu_flat_work_group_size(512, 512), amdgpu_waves_per_eu(2, 2)))
void fused_qu_smax(const unsigned short* __restrict__ qb,
                   const unsigned short* __restrict__ Ut,
                   const unsigned short* __restrict__ ab,
                   unsigned* __restrict__ rowmax,
                   unsigned* __restrict__ colmax) {
  extern __shared__ char smem[];
  unsigned short* qUs    = (unsigned short*)smem;             // 64 KB: qU tile, then stage buf B
  unsigned short* Bs2    = (unsigned short*)(smem + 65536);   // 64 KB: staging buf A
  unsigned*       colLds = (unsigned*)(smem + 131072);        // 8 KB
  unsigned*       rowLds = (unsigned*)(smem + 139264);        // 512 B

  const int tid = threadIdx.x;
  const int b = blockIdx.x, tm = blockIdx.y;

  const int lane = tid & 63;
  const int m16  = lane & 15;
  const int quad = lane >> 4;
  const int wave = tid >> 6;          // 0..7
  const int wm   = wave >> 2;         // phase 1: 0..1 (row half)
  const int wn   = wave & 3;          // phase 1: 0..3
  const int wr   = wave >> 1;         // phase 2: 0..3 (32-row group)
  const int wc   = wave & 1;          // phase 2: 0..1 (64-col group)
  const int srow = tid >> 3;          // staging row (64/issue)
  const int scol = (((tid & 7) ^ (srow & 7))) * 8;   // swizzled source chunk

  #pragma unroll
  for (int i = 0; i < 4; ++i) colLds[i * 512 + tid] = 0u;
  if (tid < 128) rowLds[tid] = 0u;

  // ================= phase 1: qU tile -> LDS (single pass) =================
  const unsigned short* Aq = qb + ((long)b * 2048 + tm * 128) * 256;
  unsigned short* S1 = Bs2;            // 16 KB: A 128x64
  unsigned short* S2 = Bs2 + 8192;     // 32 KB: B 256x64
  {
    f4v acc[4][4] = {};
    for (int kt = 0; kt < 4; ++kt) {
      const int k0 = kt * 64;
      __syncthreads();                 // staging region free
      #pragma unroll
      for (int i = 0; i < 2; ++i)
        gload_lds16(Aq + (long)(i * 64 + srow) * 256 + k0 + scol, &S1[i * 4096 + tid * 8]);
      #pragma unroll
      for (int i = 0; i < 4; ++i)
        gload_lds16(Ut + (long)(i * 64 + srow) * 256 + k0 + scol, &S2[i * 4096 + tid * 8]);
      __syncthreads();                 // staging complete
      #pragma unroll
      for (int kk = 0; kk < 2; ++kk) {
        const int cs = ((kk * 4 + quad) ^ (m16 & 7)) * 8;
        s8v af[4], bfv[4];
        #pragma unroll
        for (int i = 0; i < 4; ++i)
          af[i] = *(const s8v*)&S1[(wm * 64 + i * 16 + m16) * 64 + cs];
        #pragma unroll
        for (int j = 0; j < 4; ++j)
          bfv[j] = *(const s8v*)&S2[(wn * 64 + j * 16 + m16) * 64 + cs];
        #pragma unroll
        for (int i = 0; i < 4; ++i)
          #pragma unroll
          for (int j = 0; j < 4; ++j)
            acc[i][j] = __builtin_amdgcn_mfma_f32_16x16x32_bf16(af[i], bfv[j], acc[i][j], 0, 0, 0);
      }
    }
    // write acc -> qUs (row-major 256 cols, swizzled 16B chunks)
    // C/D layout: col = lane&15, row = quad*4 + reg (verified mapping)
    #pragma unroll
    for (int i = 0; i < 4; ++i)
      #pragma unroll
      for (int r = 0; r < 4; ++r) {
        const int lr = wm * 64 + i * 16 + quad * 4 + r;
        #pragma unroll
        for (int j = 0; j < 4; ++j) {
          const int col = wn * 64 + j * 16 + m16;
          const int ch = (col >> 3) ^ (lr & 7);
          qUs[lr * 256 + ch * 8 + (col & 7)] = f2bf(acc[i][j][r]);
        }
      }
  }
  __syncthreads();   // qUs complete; Bs2 free for phase 2

  // ================= phase 2: 16 a-tiles vs register-resident qU =================
  const unsigned short* Ab_ = ab + (long)b * 2048 * 256;
  const int wr32 = wr * 32;
  const int wc64 = wc * 64;

#define STAGE_TILE(tb, dst) do {                                               \
    _Pragma("unroll")                                                          \
    for (int e_ = 0; e_ < 8; ++e_) {                                           \
      const int u_ = e_ * 512 + tid;                                           \
      const int row_ = u_ >> 5;                                                \
      const int chs_ = (u_ & 31) ^ (row_ & 7);                                 \
      gload_lds16(Ab_ + (long)((tb) * 128 + row_) * 256 + chs_ * 8,            \
                  &(dst)[u_ * 8]);                                             \
    }                                                                          \
  } while (0)

#define COMPUTE_TILE(tb, buf) do {                                             \
    f4v acc[2][4] = {};                                                        \
    _Pragma("unroll")                                                          \
    for (int kq_ = 0; kq_ < 8; ++kq_) {                                        \
      const int cs_ = ((kq_ * 4 + quad) ^ (m16 & 7)) * 8;                      \
      _Pragma("unroll")                                                        \
      for (int j_ = 0; j_ < 4; ++j_) {                                         \
        const s8v bv_ = *(const s8v*)&(buf)[(wc64 + j_ * 16 + m16) * 256 + cs_]; \
        acc[0][j_] = __builtin_amdgcn_mfma_f32_16x16x32_bf16(aq[0][kq_], bv_, acc[0][j_], 0, 0, 0); \
        acc[1][j_] = __builtin_amdgcn_mfma_f32_16x16x32_bf16(aq[1][kq_], bv_, acc[1][j_], 0, 0, 0); \
      }                                                                        \
    }                                                                          \
    _Pragma("unroll")                                                          \
    for (int i_ = 0; i_ < 2; ++i_)                                             \
      _Pragma("unroll")                                                        \
      for (int r_ = 0; r_ < 4; ++r_)                                           \
        rmx[i_][r_] = fmaxf(rmx[i_][r_],                                       \
          fmaxf(fmaxf(acc[i_][0][r_], acc[i_][1][r_]),                         \
                fmaxf(acc[i_][2][r_], acc[i_][3][r_])));                       \
    _Pragma("unroll")                                                          \
    for (int j_ = 0; j_ < 4; ++j_) {                                           \
      float v_ = fmaxf(fmaxf(acc[0][j_][0], acc[0][j_][1]),                    \
                       fmaxf(acc[0][j_][2], acc[0][j_][3]));                   \
      v_ = fmaxf(v_, fmaxf(fmaxf(acc[1][j_][0], acc[1][j_][1]),                \
                           fmaxf(acc[1][j_][2], acc[1][j_][3])));              \
      v_ = fmaxf(v_, __shfl_xor(v_, 16));                                      \
      v_ = fmaxf(v_, __shfl_xor(v_, 32));                                      \
      if (quad == 0)                                                           \
        atomicMax(&colLds[(tb) * 128 + wc64 + j_ * 16 + m16], encf(v_));       \
    }                                                                          \
  } while (0)

  // issue tile-0 staging first so the globals fly during the A-frag hoist
  STAGE_TILE(0, Bs2);

  // hoist qU A-fragments: invariant across all 16 tiles (aq[2][8] = 64 VGPRs)
  s8v aq[2][8];
  #pragma unroll
  for (int kq = 0; kq < 8; ++kq) {
    const int cs = ((kq * 4 + quad) ^ (m16 & 7)) * 8;
    aq[0][kq] = *(const s8v*)&qUs[(wr32 + m16) * 256 + cs];
    aq[1][kq] = *(const s8v*)&qUs[(wr32 + 16 + m16) * 256 + cs];
  }
  // all waves must have their qU reads DATA-RETURNED before qUs is restaged
  asm volatile("s_waitcnt lgkmcnt(0)" ::: "memory");
  __builtin_amdgcn_s_barrier();

  float rmx[2][4];
  #pragma unroll
  for (int i = 0; i < 2; ++i)
    #pragma unroll
    for (int r = 0; r < 4; ++r) rmx[i][r] = -3.4e38f;

  // double-buffered pipeline: stage(t+1) issued BEFORE compute(t); counted
  // vmcnt(8) keeps the next tile's 8 loads in flight across the barrier.
  #pragma unroll 1
  for (int t2 = 0; t2 < 8; ++t2) {
    const int te = t2 * 2;
    // ---- even tile: compute Bs2, stage te+1 -> qUs-region ----
    STAGE_TILE(te + 1, qUs);
    asm volatile("s_waitcnt vmcnt(8)" ::: "memory");   // tile te's loads landed
    __builtin_amdgcn_s_barrier();
    COMPUTE_TILE(te, Bs2);
    __builtin_amdgcn_s_barrier();                      // Bs2 reads done -> restage-safe
    // ---- odd tile: compute qUs-region, stage te+2 -> Bs2 ----
    if (te + 2 < 16) {
      STAGE_TILE(te + 2, Bs2);
      asm volatile("s_waitcnt vmcnt(8)" ::: "memory"); // tile te+1's loads landed
    } else {
      asm volatile("s_waitcnt vmcnt(0)" ::: "memory"); // drain for last tile
    }
    __builtin_amdgcn_s_barrier();
    COMPUTE_TILE(te + 1, qUs);
    __builtin_amdgcn_s_barrier();                      // qUs reads done -> restage-safe
  }

  // ---- final row maxes: shuffle over m16, combine wc-waves via LDS, store ----
  #pragma unroll
  for (int i = 0; i < 2; ++i)
    #pragma unroll
    for (int r = 0; r < 4; ++r) {
      float v = rmx[i][r];
      #pragma unroll
      for (int d2 = 1; d2 < 16; d2 <<= 1) v = fmaxf(v, __shfl_xor(v, d2));
      if (m16 == 0) atomicMax(&rowLds[wr32 + i * 16 + quad * 4 + r], encf(v));
    }
  __syncthreads();
  if (tid < 128)
    rowmax[(long)b * 2048 + tm * 128 + tid] = rowLds[tid];   // plain store (block owns rows)
  // ---- col maxes: one global atomic pass ----
  #pragma unroll
  for (int i = 0; i < 4; ++i)
    atomicMax(&colmax[(long)b * 2048 + i * 512 + tid], colLds[i * 512 + tid]);
}

// ---------- fused softmax + weighted sum (bf16 inputs, 16B/lane loads) ----------
__global__ void wsum_kernel(const uint4* __restrict__ qb, const uint4* __restrict__ ab,
                            const unsigned* __restrict__ rowmax, const unsigned* __restrict__ colmax,
                            float* __restrict__ out) {
  const int tid = threadIdx.x;
  const int chunk = blockIdx.x;
  const int b = blockIdx.y;
  const int z = blockIdx.z;
  const unsigned* e = z ? colmax : rowmax;
  const uint4* src = z ? ab : qb;

  __shared__ float sm[4];
  __shared__ float ss[4];
  __shared__ float wLds[128];
  __shared__ float red[256 * 8];   // 8 KB

  float x[8];
  float m = -3.4e38f;
  #pragma unroll
  for (int j = 0; j < 8; ++j) {
    x[j] = tanhf(decf(e[b * 2048 + j * 256 + tid]));
    m = fmaxf(m, x[j]);
  }
  #pragma unroll
  for (int d2 = 1; d2 < 64; d2 <<= 1) m = fmaxf(m, __shfl_xor(m, d2));
  if ((tid & 63) == 0) sm[tid >> 6] = m;
  __syncthreads();
  m = fmaxf(fmaxf(sm[0], sm[1]), fmaxf(sm[2], sm[3]));
  float s = 0.f;
  #pragma unroll
  for (int j = 0; j < 8; ++j) s += expf(x[j] - m);
  #pragma unroll
  for (int d2 = 1; d2 < 64; d2 <<= 1) s += __shfl_xor(s, d2);
  if ((tid & 63) == 0) ss[tid >> 6] = s;
  __syncthreads();
  const float inv = 1.f / (ss[0] + ss[1] + ss[2] + ss[3]);

  if (tid < 128) {
    float xv = tanhf(decf(e[b * 2048 + chunk * 128 + tid]));
    wLds[tid] = expf(xv - m) * inv;
  }
  __syncthreads();

  const int dg = tid & 31;
  const int rg = tid >> 5;       // 0..7, rows stride 8
  float acc[8] = {};
  const long rowbase = (long)b * 2048 + chunk * 128;
  for (int t = rg; t < 128; t += 8) {
    const float wgt = wLds[t];
    uint4 v = src[(rowbase + t) * 32 + dg];
    acc[0] += wgt * __uint_as_float(v.x << 16);
    acc[1] += wgt * __uint_as_float(v.x & 0xFFFF0000u);
    acc[2] += wgt * __uint_as_float(v.y << 16);
    acc[3] += wgt * __uint_as_float(v.y & 0xFFFF0000u);
    acc[4] += wgt * __uint_as_float(v.z << 16);
    acc[5] += wgt * __uint_as_float(v.z & 0xFFFF0000u);
    acc[6] += wgt * __uint_as_float(v.w << 16);
    acc[7] += wgt * __uint_as_float(v.w & 0xFFFF0000u);
  }
  #pragma unroll
  for (int k = 0; k < 8; ++k) red[tid * 8 + k] = acc[k];
  __syncthreads();
  if (tid < 32) {
    #pragma unroll
    for (int k = 0; k < 8; ++k) {
      float v = 0.f;
      #pragma unroll
      for (int g = 0; g < 8; ++g) v += red[((g << 5) | tid) * 8 + k];
      atomicAdd(&out[z * 4096 + b * 256 + tid * 8 + k], v);
    }
  }
}

// ---------- launch ----------
extern "C" void kernel_launch(void* const* d_in, const int* in_sizes, int n_in,
                              void* d_out, int out_size, void* d_ws, size_t ws_size,
                              hipStream_t stream) {
  const float* q = (const float*)d_in[0];
  const float* a = (const float*)d_in[1];
  const float* U = (const float*)d_in[2];
  float* out = (float*)d_out;

  char* w = (char*)d_ws;
  unsigned short* qb = (unsigned short*)w;                       // 16 MB
  unsigned short* ab = (unsigned short*)(w + (16ull << 20));     // 16 MB
  unsigned short* Ut = (unsigned short*)(w + (32ull << 20));     // 128 KB
  unsigned* rmax = (unsigned*)(w + (32ull << 20) + (128ull << 10));
  unsigned* cmax = rmax + 32768;

  // allow 139776 B dynamic LDS for the fused kernel (host-side, idempotent)
  constexpr int SMEM = 139776;
  hipFuncSetAttribute((const void*)fused_qu_smax,
                      hipFuncAttributeMaxDynamicSharedMemorySize, SMEM);

  // fused q/a bf16-cast + U transpose + rmax/cmax zero + out zero
  convert_kernel<<<8352, 256, 0, stream>>>((const float4*)q, (const float4*)a, U,
                                           (ushort4*)qb, (ushort4*)ab, Ut, rmax, out);

  // qU tile in LDS + S row/col maxes; grid (b, tm) -> XCD == b%8; 8 waves/block
  fused_qu_smax<<<dim3(16, 16), 512, SMEM, stream>>>(qb, Ut, ab, rmax, cmax);

  // fused softmax + weighted pooling (bf16, 16B/lane)
  wsum_kernel<<<dim3(16, 16, 2), 256, 0, stream>>>((const uint4*)qb, (const uint4*)ab,
                                                   rmax, cmax, out);
}